// Round 3
// baseline (410.168 us; speedup 1.0000x reference)
//
#include <hip/hip_runtime.h>
#include <math.h>

// B=64, S=128, F=136, H=128
// ws layout (floats):
//   reprs [8192*128], R1p [8192*128], GIp [8192*384],
//   WihT [128*384], WhhT [128*384], gi0 [384], h1 [64*128]

__global__ void k_prep(const float* __restrict__ Wih, const float* __restrict__ Whh,
                       const float* __restrict__ bih, const float* __restrict__ go,
                       float* __restrict__ WihT, float* __restrict__ WhhT,
                       float* __restrict__ gi0) {
  const int t = blockIdx.x * blockDim.x + threadIdx.x;
  const int n = 384 * 128;
  for (int i = t; i < n; i += gridDim.x * blockDim.x) {
    const int k = i / 384, o = i % 384;          // writes coalesced over o
    WihT[i] = Wih[o * 128 + k];
    WhhT[i] = Whh[o * 128 + k];
  }
  if (blockIdx.x == 0) {
    for (int o = threadIdx.x; o < 384; o += blockDim.x) {
      float acc = bih[o];
      for (int k = 0; k < 128; ++k) acc += go[k] * Wih[o * 128 + k];
      gi0[o] = acc;
    }
  }
}

// reprs = ReLU(x@W1+b1)@W2+b2 ; 8 rows per 128-thread block
__global__ void k_reprs(const float* __restrict__ x, const float* __restrict__ W1,
                        const float* __restrict__ b1, const float* __restrict__ W2,
                        const float* __restrict__ b2, float* __restrict__ reprs) {
  __shared__ float xs[8][136];
  __shared__ float hid[8][128];
  const int j = threadIdx.x;
  const int row0 = blockIdx.x * 8;
  for (int i = j; i < 8 * 136; i += 128) xs[i / 136][i % 136] = x[row0 * 136 + i];
  __syncthreads();
  float acc[8];
  {
    const float bb = b1[j];
#pragma unroll
    for (int r = 0; r < 8; ++r) acc[r] = bb;
    for (int k = 0; k < 136; ++k) {
      const float w = W1[k * 128 + j];        // coalesced, W1 read once per block
#pragma unroll
      for (int r = 0; r < 8; ++r) acc[r] += xs[r][k] * w;
    }
#pragma unroll
    for (int r = 0; r < 8; ++r) hid[r][j] = fmaxf(acc[r], 0.f);
  }
  __syncthreads();
  {
    const float bb = b2[j];
#pragma unroll
    for (int r = 0; r < 8; ++r) acc[r] = bb;
    for (int k = 0; k < 128; ++k) {
      const float w = W2[k * 128 + j];
#pragma unroll
      for (int r = 0; r < 8; ++r) acc[r] += hid[r][k] * w;
    }
#pragma unroll
    for (int r = 0; r < 8; ++r) reprs[(row0 + r) * 128 + j] = acc[r];
  }
}

// R1p = reprs@com_W1 + com_b1 ; GIp = reprs@Wih.T + bih ; 8 rows per block
__global__ void k_proj(const float* __restrict__ reprs, const float* __restrict__ comW1,
                       const float* __restrict__ comb1, const float* __restrict__ WihT,
                       const float* __restrict__ bih, float* __restrict__ R1p,
                       float* __restrict__ GIp) {
  __shared__ float xs[8][128];
  const int j = threadIdx.x;
  const int row0 = blockIdx.x * 8;
  for (int i = j; i < 8 * 128; i += 128) xs[i >> 7][i & 127] = reprs[row0 * 128 + i];
  __syncthreads();
  float acc[8];
  const float cb = comb1[j];
#pragma unroll
  for (int r = 0; r < 8; ++r) acc[r] = cb;
  for (int k = 0; k < 128; ++k) {
    const float w = comW1[k * 128 + j];
#pragma unroll
    for (int r = 0; r < 8; ++r) acc[r] += xs[r][k] * w;
  }
#pragma unroll
  for (int r = 0; r < 8; ++r) R1p[(row0 + r) * 128 + j] = acc[r];
  for (int oo = 0; oo < 3; ++oo) {
    const int o = oo * 128 + j;
    const float bb = bih[o];
#pragma unroll
    for (int r = 0; r < 8; ++r) acc[r] = bb;
    for (int k = 0; k < 128; ++k) {
      const float w = WihT[k * 384 + o];
#pragma unroll
      for (int r = 0; r < 8; ++r) acc[r] += xs[r][k] * w;
    }
#pragma unroll
    for (int r = 0; r < 8; ++r) GIp[(row0 + r) * 384 + o] = acc[r];
  }
}

// h1 = GRU(go, sigmoid(mlp2(cat(max_S, mean_S)))) ; one block per batch
__global__ void k_h1(const float* __restrict__ reprs,
                     const float* __restrict__ cntW1, const float* __restrict__ cntb1,
                     const float* __restrict__ cntW2, const float* __restrict__ cntb2,
                     const float* __restrict__ WhhT, const float* __restrict__ bhh,
                     const float* __restrict__ gi0, float* __restrict__ h1) {
  const int b = blockIdx.x, j = threadIdx.x;
  __shared__ float mx[128], mn[128], hid[128], h0s[128], ghs[384];
  float vmax = -INFINITY, vsum = 0.f;
  for (int s = 0; s < 128; ++s) {
    const float v = reprs[(b * 128 + s) * 128 + j];
    vmax = fmaxf(vmax, v);
    vsum += v;
  }
  mx[j] = vmax;
  mn[j] = vsum * (1.0f / 128.0f);
  __syncthreads();
  float acc = cntb1[j];
  for (int k = 0; k < 128; ++k) acc += mx[k] * cntW1[k * 128 + j];
  for (int k = 0; k < 128; ++k) acc += mn[k] * cntW1[(128 + k) * 128 + j];
  hid[j] = fmaxf(acc, 0.f);
  __syncthreads();
  float acc2 = cntb2[j];
  for (int k = 0; k < 128; ++k) acc2 += hid[k] * cntW2[k * 128 + j];
  h0s[j] = 1.f / (1.f + expf(-acc2));
  __syncthreads();
  for (int oo = 0; oo < 3; ++oo) {
    const int og = oo * 128 + j;
    float a = bhh[og];
    for (int k = 0; k < 128; ++k) a += h0s[k] * WhhT[k * 384 + og];
    ghs[og] = a;
  }
  __syncthreads();
  const float ir = gi0[j], iz = gi0[j + 128], inn = gi0[j + 256];
  const float hr = ghs[j], hz = ghs[j + 128], hn = ghs[j + 256];
  const float rr = 1.f / (1.f + expf(-(ir + hr)));
  const float zz = 1.f / (1.f + expf(-(iz + hz)));
  const float nn = tanhf(inn + rr * hn);
  h1[b * 128 + j] = (1.f - zz) * nn + zz * h0s[j];
}

// Sequential decode: one block (512 thr) per batch, 128 steps.
// thread (o = t>>2, q = t&3): owns output o (and gh outputs 3o..3o+2), k-slice q*32..q*32+31.
__global__ __launch_bounds__(512) void k_decode(
    const float* __restrict__ R1p, const float* __restrict__ GIp,
    const float* __restrict__ h1, const float* __restrict__ comW1,
    const float* __restrict__ comW2, const float* __restrict__ comb2,
    const float* __restrict__ WhhT, const float* __restrict__ bhh,
    float* __restrict__ out) {
  const int b = blockIdx.x;
  const int t = threadIdx.x;
  const int o = t >> 2;
  const int q = t & 3;
  const int kb = q * 32;
  __shared__ float R1s[128][132];   // +4 pad keeps rows 16B-aligned, spreads banks
  __shared__ float hsh[128];
  __shared__ float hw1[128];
  __shared__ float ghs[384];
  __shared__ float sc[128];
  __shared__ float maskv[128];      // additive mask: 0 or -inf
  __shared__ int selIdx;

  for (int i = t; i < 128 * 128; i += 512) R1s[i >> 7][i & 127] = R1p[b * 16384 + i];
  if (t < 128) { hsh[t] = h1[b * 128 + t]; maskv[t] = 0.0f; }

  // persistent weights in registers (~160 VGPR)
  float wCom[32], wW2[32], wWhh0[32], wWhh1[32], wWhh2[32];
#pragma unroll
  for (int j = 0; j < 32; ++j) {
    wCom[j] = comW1[(kb + j) * 128 + o];
    wW2[j] = comW2[kb + j];
    wWhh0[j] = WhhT[(kb + j) * 384 + (o * 3 + 0)];
    wWhh1[j] = WhhT[(kb + j) * 384 + (o * 3 + 1)];
    wWhh2[j] = WhhT[(kb + j) * 384 + (o * 3 + 2)];
  }
  const float vb0 = bhh[o * 3 + 0], vb1 = bhh[o * 3 + 1], vb2 = bhh[o * 3 + 2];
  const float scb2 = comb2[0];
  float pw = 1.0f;
  __syncthreads();

  for (int step = 0; step < 128; ++step) {
    // hw1 = h@com_W1 and gh = h@Whh.T (+bhh) — both independent of selection
    float a0 = 0.f, g0 = 0.f, g1 = 0.f, g2 = 0.f;
#pragma unroll
    for (int j = 0; j < 32; ++j) {
      const float hv = hsh[kb + j];
      a0 += hv * wCom[j];
      g0 += hv * wWhh0[j];
      g1 += hv * wWhh1[j];
      g2 += hv * wWhh2[j];
    }
    a0 += __shfl_xor(a0, 1); a0 += __shfl_xor(a0, 2);
    g0 += __shfl_xor(g0, 1); g0 += __shfl_xor(g0, 2);
    g1 += __shfl_xor(g1, 1); g1 += __shfl_xor(g1, 2);
    g2 += __shfl_xor(g2, 1); g2 += __shfl_xor(g2, 2);
    if (q == 0) {
      hw1[o] = a0;
      ghs[o * 3 + 0] = g0 + vb0;
      ghs[o * 3 + 1] = g1 + vb1;
      ghs[o * 3 + 2] = g2 + vb2;
    }
    __syncthreads();
    // scores: s_o = ReLU(R1[o,:]+hw1)·w2 + b2 + mask
    float acc = 0.f;
#pragma unroll
    for (int j = 0; j < 32; ++j)
      acc += fmaxf(R1s[o][kb + j] + hw1[kb + j], 0.f) * wW2[j];
    acc += __shfl_xor(acc, 1); acc += __shfl_xor(acc, 2);
    if (q == 0) sc[o] = acc + scb2 + maskv[o];
    __syncthreads();
    // argmax (first-max / lowest-index tie-break, matching jnp.argmax)
    if (t < 64) {
      float v = sc[t];
      int idx = t;
      const float v1 = sc[t + 64];
      if (v1 > v) { v = v1; idx = t + 64; }
#pragma unroll
      for (int d = 1; d < 64; d <<= 1) {
        const float vo = __shfl_xor(v, d);
        const int io = __shfl_xor(idx, d);
        if (vo > v || (vo == v && io < idx)) { v = vo; idx = io; }
      }
      if (t == 0) {
        selIdx = idx;
        maskv[idx] = -INFINITY;
        out[b * 128 + idx] = pw;   // 0.9^step at the selected doc
      }
    }
    pw *= 0.9f;
    __syncthreads();
    // GRU combine: gi gathered from precomputed GIp row
    if (t < 128) {
      const float* gi = GIp + (b * 128 + selIdx) * 384;
      const float ir = gi[t], iz = gi[t + 128], inn = gi[t + 256];
      const float hr = ghs[t], hz = ghs[t + 128], hn = ghs[t + 256];
      const float rr = 1.f / (1.f + expf(-(ir + hr)));
      const float zz = 1.f / (1.f + expf(-(iz + hz)));
      const float nn = tanhf(inn + rr * hn);
      hsh[t] = (1.f - zz) * nn + zz * hsh[t];
    }
    __syncthreads();
  }
}

extern "C" void kernel_launch(void* const* d_in, const int* in_sizes, int n_in,
                              void* d_out, int out_size, void* d_ws, size_t ws_size,
                              hipStream_t stream) {
  const float* x     = (const float*)d_in[0];
  const float* fnnW1 = (const float*)d_in[2];
  const float* fnnb1 = (const float*)d_in[3];
  const float* fnnW2 = (const float*)d_in[4];
  const float* fnnb2 = (const float*)d_in[5];
  const float* cntW1 = (const float*)d_in[6];
  const float* cntb1 = (const float*)d_in[7];
  const float* cntW2 = (const float*)d_in[8];
  const float* cntb2 = (const float*)d_in[9];
  const float* comW1 = (const float*)d_in[10];
  const float* comb1 = (const float*)d_in[11];
  const float* comW2 = (const float*)d_in[12];
  const float* comb2 = (const float*)d_in[13];
  const float* Wih   = (const float*)d_in[14];
  const float* Whh   = (const float*)d_in[15];
  const float* bih   = (const float*)d_in[16];
  const float* bhh   = (const float*)d_in[17];
  const float* go    = (const float*)d_in[18];
  float* out = (float*)d_out;

  float* ws    = (float*)d_ws;
  float* reprs = ws;                  // 1048576
  float* R1p   = reprs + 1048576;     // 1048576
  float* GIp   = R1p + 1048576;       // 3145728
  float* WihT  = GIp + 3145728;       // 49152
  float* WhhT  = WihT + 49152;        // 49152
  float* gi0   = WhhT + 49152;        // 384
  float* h1    = gi0 + 384;           // 8192

  hipLaunchKernelGGL(k_prep, dim3(64), dim3(256), 0, stream, Wih, Whh, bih, go,
                     WihT, WhhT, gi0);
  hipLaunchKernelGGL(k_reprs, dim3(1024), dim3(128), 0, stream, x, fnnW1, fnnb1,
                     fnnW2, fnnb2, reprs);
  hipLaunchKernelGGL(k_proj, dim3(1024), dim3(128), 0, stream, reprs, comW1, comb1,
                     WihT, bih, R1p, GIp);
  hipLaunchKernelGGL(k_h1, dim3(64), dim3(128), 0, stream, reprs, cntW1, cntb1,
                     cntW2, cntb2, WhhT, bhh, gi0, h1);
  hipLaunchKernelGGL(k_decode, dim3(64), dim3(512), 0, stream, R1p, GIp, h1, comW1,
                     comW2, comb2, WhhT, bhh, out);
}